// Round 6
// baseline (153.997 us; speedup 1.0000x reference)
//
#include <hip/hip_runtime.h>
#include <hip/hip_bf16.h>
#include <math.h>

// ---------------------------------------------------------------------------
// MAB block. Attention: 32x32x16 MFMA, swapped QK^T (lane-local softmax),
// NO max-shift (softmax shift-invariance; scores bounded far below fp32
// overflow), row-sums via ones-MFMA, KV-split x2 for occupancy (4 waves/SIMD),
// partials merged by k_comb.
// ---------------------------------------------------------------------------

typedef __attribute__((ext_vector_type(4))) float f32x4;
typedef __attribute__((ext_vector_type(16))) float f32x16;
typedef __attribute__((ext_vector_type(8))) short s16x8;
typedef __attribute__((ext_vector_type(2))) unsigned u32x2;

#define MFMA_BF16(A, B, C) __builtin_amdgcn_mfma_f32_16x16x32_bf16((A), (B), (C), 0, 0, 0)
#define MFMA32(A, B, C) __builtin_amdgcn_mfma_f32_32x32x16_bf16((A), (B), (C), 0, 0, 0)

static __device__ __forceinline__ unsigned short f2bf(float f) {
    union { float f; unsigned u; } v; v.f = f;
    unsigned u = v.u;
    unsigned r = (u + 0x7FFFu + ((u >> 16) & 1u)) >> 16;  // RNE
    return (unsigned short)r;
}

static __device__ __forceinline__ float bf2f(unsigned short b) {
    union { unsigned u; float f; } v; v.u = ((unsigned)b) << 16;
    return v.f;
}

static __device__ __forceinline__ unsigned cvtpk(float lo, float hi) {
    unsigned r;
    asm("v_cvt_pk_bf16_f32 %0, %1, %2" : "=v"(r) : "v"(lo), "v"(hi));
    return r;
}

static __device__ __forceinline__ s16x8 mk8(unsigned a, unsigned b, unsigned c, unsigned d) {
    union { unsigned u[4]; s16x8 v; } x;
    x.u[0] = a; x.u[1] = b; x.u[2] = c; x.u[3] = d;
    return x.v;
}

// ---- merged fp32 -> bf16 convert: Q, K, and the 4 weight matrices ----
__global__ __launch_bounds__(256) void k_cvt_all(
    const float* __restrict__ Q, const float* __restrict__ K,
    const float* __restrict__ Wq, const float* __restrict__ Wk,
    const float* __restrict__ Wv, const float* __restrict__ Wo,
    unsigned short* __restrict__ Qb, unsigned short* __restrict__ Kb,
    unsigned short* __restrict__ Wqb, unsigned short* __restrict__ Wkb,
    unsigned short* __restrict__ Wvb, unsigned short* __restrict__ Wob) {
    int bid = blockIdx.x, tid = threadIdx.x;
    const float* src;
    unsigned short* dst;
    int idx;
    if (bid < 2048) {
        src = Q; dst = Qb; idx = bid * 256 + tid;
    } else if (bid < 4096) {
        src = K; dst = Kb; idx = (bid - 2048) * 256 + tid;
    } else {
        int w = (bid - 4096) >> 6;
        src = (w == 0) ? Wq : (w == 1) ? Wk : (w == 2) ? Wv : Wo;
        dst = (w == 0) ? Wqb : (w == 1) ? Wkb : (w == 2) ? Wvb : Wob;
        idx = ((bid - 4096) & 63) * 256 + tid;
    }
    float4 v = ((const float4*)src)[idx];
    ushort4 o;
    o.x = f2bf(v.x); o.y = f2bf(v.y); o.z = f2bf(v.z); o.w = f2bf(v.w);
    ((ushort4*)dst)[idx] = o;
}

// ---- merged projections: Q-proj(rm) + K-proj(rm) + V-proj(transposed) ----
__global__ __launch_bounds__(128) void k_proj(
    const unsigned short* __restrict__ Qb, const unsigned short* __restrict__ Kb,
    const unsigned short* __restrict__ Wqb, const unsigned short* __restrict__ Wkb,
    const unsigned short* __restrict__ Wvb,
    const float* __restrict__ bq, const float* __restrict__ bk, const float* __restrict__ bv,
    unsigned short* __restrict__ Qp, unsigned short* __restrict__ Kp,
    unsigned short* __restrict__ Vtp, float qscale) {
    const int wv = threadIdx.x >> 6, lid = threadIdx.x & 63;
    const int i = lid & 15, G = lid >> 4;
    const int bid = blockIdx.x;
    if (bid < 512) {
        const int which = bid >> 8;
        const unsigned short* X = which ? Kb : Qb;
        const unsigned short* W = which ? Wkb : Wqb;
        const float* bias = which ? bk : bq;
        unsigned short* Y = which ? Kp : Qp;
        const float scale = which ? 1.0f : qscale;
        const int m0 = (bid & 255) * 32 + wv * 16;
        f32x4 acc[16];
#pragma unroll
        for (int nf = 0; nf < 16; ++nf) acc[nf] = f32x4{0.f, 0.f, 0.f, 0.f};
        const unsigned short* Xrow = X + (size_t)(m0 + i) * 256;
#pragma unroll
        for (int k0 = 0; k0 < 256; k0 += 32) {
            s16x8 a = *(const s16x8*)(Xrow + k0 + G * 8);
#pragma unroll
            for (int nf = 0; nf < 16; ++nf) {
                s16x8 b = *(const s16x8*)(W + (size_t)(nf * 16 + i) * 256 + k0 + G * 8);
                acc[nf] = MFMA_BF16(a, b, acc[nf]);
            }
        }
#pragma unroll
        for (int nf = 0; nf < 16; ++nf) {
            int col = nf * 16 + i;
            float bvv = bias[col];
            int h = col >> 5, dh = col & 31;
#pragma unroll
            for (int r = 0; r < 4; ++r) {
                int m = m0 + G * 4 + r;
                int bb = m >> 12, n = m & 4095;
                float v = (acc[nf][r] + bvv) * scale;
                Y[(size_t)(((bb << 3) + h) * 4096 + n) * 32 + dh] = f2bf(v);
            }
        }
    } else {
        const int tid = bid - 512;                  // [0, 1024)
        const int n0 = (tid & 127) * 64;            // 8192 rows
        const int dv0 = (tid >> 7) * 32 + wv * 16;  // 256 dv
        f32x4 acc[4];
#pragma unroll
        for (int nf = 0; nf < 4; ++nf) acc[nf] = f32x4{0.f, 0.f, 0.f, 0.f};
        const unsigned short* Wrow = Wvb + (size_t)(dv0 + i) * 256;
#pragma unroll
        for (int k0 = 0; k0 < 256; k0 += 32) {
            s16x8 a = *(const s16x8*)(Wrow + k0 + G * 8);
#pragma unroll
            for (int nf = 0; nf < 4; ++nf) {
                s16x8 b = *(const s16x8*)(Kb + (size_t)(n0 + nf * 16 + i) * 256 + k0 + G * 8);
                acc[nf] = MFMA_BF16(a, b, acc[nf]);
            }
        }
#pragma unroll
        for (int r = 0; r < 4; ++r) {
            int dv = dv0 + G * 4 + r;
            float bvv = bv[dv];
            int h = dv >> 5, dh = dv & 31;
#pragma unroll
            for (int nf = 0; nf < 4; ++nf) {
                int n = n0 + nf * 16 + i;
                int bb = n >> 12, nn = n & 4095;
                Vtp[(size_t)(((bb << 3) + h) * 32 + dh) * 4096 + nn] = f2bf(acc[nf][r] + bvv);
            }
        }
    }
}

// ---- softmax + PV body for one 32-wide KV tile (no max-shift) ----
static __device__ __forceinline__ void softmax_pv(
    f32x16& st, f32x16& acc, f32x16& accL,
    const s16x8 v0, const s16x8 v1, const s16x8 ones) {
#pragma unroll
    for (int r = 0; r < 16; ++r) st[r] = __builtin_amdgcn_exp2f(st[r]);
    unsigned w00 = cvtpk(st[0], st[1]),   w01 = cvtpk(st[2], st[3]);
    unsigned w10 = cvtpk(st[4], st[5]),   w11 = cvtpk(st[6], st[7]);
    unsigned w20 = cvtpk(st[8], st[9]),   w21 = cvtpk(st[10], st[11]);
    unsigned w30 = cvtpk(st[12], st[13]), w31 = cvtpk(st[14], st[15]);
    u32x2 sA0 = __builtin_amdgcn_permlane32_swap(w00, w10, false, false);
    u32x2 sB0 = __builtin_amdgcn_permlane32_swap(w01, w11, false, false);
    u32x2 sA1 = __builtin_amdgcn_permlane32_swap(w20, w30, false, false);
    u32x2 sB1 = __builtin_amdgcn_permlane32_swap(w21, w31, false, false);
    s16x8 pa0 = mk8(sA0[0], sB0[0], sA0[1], sB0[1]);  // P, j half 0
    s16x8 pa1 = mk8(sA1[0], sB1[0], sA1[1], sB1[1]);  // P, j half 1
    acc  = MFMA32(pa0, v0, acc);
    acc  = MFMA32(pa1, v1, acc);
    accL = MFMA32(pa0, ones, accL);  // row-sums ride the MFMA pipe
    accL = MFMA32(pa1, ones, accL);
}

// ---- flash attention, KV-split x2: 1024 blocks, each 2048 keys ----
// Writes normalized bf16 partial O (per split) + fp32 row-sums L.
__global__ __launch_bounds__(256, 4) void k_attn(const unsigned short* __restrict__ Qp,
                                                 const unsigned short* __restrict__ Kp,
                                                 const unsigned short* __restrict__ Vt,
                                                 unsigned short* __restrict__ Ob,
                                                 float* __restrict__ Lb) {
    const int wv = threadIdx.x >> 6, l = threadIdx.x & 63;
    const int ql = l & 31, hi = l >> 5;
    int bid = blockIdx.x;
    int wg = ((bid & 7) << 7) | (bid >> 3);  // XCD swizzle, 1024 % 8 == 0, bijective
    int bh = wg >> 6;
    int rest = wg & 63;
    int qblk = rest >> 1, sp = rest & 1;
    const unsigned short* Qh = Qp + (size_t)bh * 4096 * 32;
    const unsigned short* Kh = Kp + (size_t)bh * 4096 * 32 + (size_t)sp * 2048 * 32;
    const unsigned short* Vh = Vt + (size_t)bh * 32 * 4096 + (size_t)sp * 2048;
    const int q0 = qblk * 128 + wv * 32;

    s16x8 qb0 = *(const s16x8*)(Qh + (size_t)(q0 + ql) * 32 + hi * 8);
    s16x8 qb1 = *(const s16x8*)(Qh + (size_t)(q0 + ql) * 32 + 16 + hi * 8);

    f32x16 acc, accL, Z;
#pragma unroll
    for (int r = 0; r < 16; ++r) { acc[r] = 0.f; accL[r] = 0.f; Z[r] = 0.f; }
    const s16x8 ONES = mk8(0x3F803F80u, 0x3F803F80u, 0x3F803F80u, 0x3F803F80u);

    const unsigned short* Kl = Kh + (size_t)ql * 32 + hi * 8;
    const unsigned short* Vl = Vh + (size_t)ql * 4096 + hi * 8;
    s16x8 kA0 = *(const s16x8*)(Kl + 0),    kA1 = *(const s16x8*)(Kl + 16);
    s16x8 kB0 = *(const s16x8*)(Kl + 1024), kB1 = *(const s16x8*)(Kl + 1040);
    s16x8 vA0 = *(const s16x8*)(Vl + 0),    vA1 = *(const s16x8*)(Vl + 16);
    s16x8 vB0 = *(const s16x8*)(Vl + 32),   vB1 = *(const s16x8*)(Vl + 48);

    f32x16 st = MFMA32(kA0, qb0, Z);  // tile 0
    st = MFMA32(kA1, qb1, st);
    f32x16 stn;

    for (int t = 0; t < 64; t += 2) {
        {   // tile t (A bufs); QK(t+1) from B bufs overlaps softmax(t)
            int t2 = (t + 2 < 64) ? t + 2 : 62;
            kA0 = *(const s16x8*)(Kl + (size_t)t2 * 1024);
            kA1 = *(const s16x8*)(Kl + (size_t)t2 * 1024 + 16);
            stn = MFMA32(kB0, qb0, Z);
            stn = MFMA32(kB1, qb1, stn);
            softmax_pv(st, acc, accL, vA0, vA1, ONES);
            vA0 = *(const s16x8*)(Vl + t2 * 32);
            vA1 = *(const s16x8*)(Vl + t2 * 32 + 16);
            st = stn;
        }
        {   // tile t+1 (B bufs)
            int t2 = (t + 3 < 64) ? t + 3 : 62;
            kB0 = *(const s16x8*)(Kl + (size_t)t2 * 1024);
            kB1 = *(const s16x8*)(Kl + (size_t)t2 * 1024 + 16);
            stn = MFMA32(kA0, qb0, Z);
            stn = MFMA32(kA1, qb1, stn);
            softmax_pv(st, acc, accL, vB0, vB1, ONES);
            vB0 = *(const s16x8*)(Vl + t2 * 32);
            vB1 = *(const s16x8*)(Vl + t2 * 32 + 16);
            st = stn;
        }
    }

    // store normalized partial + row-sums
    const int bb = bh >> 3, h = bh & 7;
    unsigned short* Obs = Ob + (size_t)sp * 8192 * 256;
#pragma unroll
    for (int r = 0; r < 16; ++r) {
        int qr = (r & 3) + 8 * (r >> 2) + 4 * hi;
        float o = acc[r] / accL[r];
        Obs[(size_t)((bb << 12) + q0 + qr) * 256 + h * 32 + ql] = f2bf(o);
        if (ql == 0) Lb[(size_t)(sp * 16 + bh) * 4096 + q0 + qr] = accL[r];
    }
}

// ---- combine the two KV-split partials: O = (o0*l0 + o1*l1)/(l0+l1) ----
__global__ __launch_bounds__(256) void k_comb(const unsigned short* __restrict__ Ob,
                                              const float* __restrict__ Lb,
                                              unsigned short* __restrict__ Oa) {
    int unit = blockIdx.x * 256 + threadIdx.x;  // 262144 units x 8 cols
    int m = unit >> 5;
    int c0 = (unit & 31) << 3;
    int bb = m >> 12, q = m & 4095;
    int bh = bb * 8 + (c0 >> 5);
    float l0 = Lb[(size_t)bh * 4096 + q];
    float l1 = Lb[(size_t)(16 + bh) * 4096 + q];
    float inv = 1.f / (l0 + l1);
    float w0 = l0 * inv, w1 = l1 * inv;
    const ushort4* p0 = (const ushort4*)(Ob + (size_t)m * 256 + c0);
    const ushort4* p1 = (const ushort4*)(Ob + (size_t)8192 * 256 + (size_t)m * 256 + c0);
    ushort4 a0 = p0[0], a1 = p0[1];
    ushort4 b0 = p1[0], b1 = p1[1];
    ushort4 o0, o1;
    o0.x = f2bf(bf2f(a0.x) * w0 + bf2f(b0.x) * w1);
    o0.y = f2bf(bf2f(a0.y) * w0 + bf2f(b0.y) * w1);
    o0.z = f2bf(bf2f(a0.z) * w0 + bf2f(b0.z) * w1);
    o0.w = f2bf(bf2f(a0.w) * w0 + bf2f(b0.w) * w1);
    o1.x = f2bf(bf2f(a1.x) * w0 + bf2f(b1.x) * w1);
    o1.y = f2bf(bf2f(a1.y) * w0 + bf2f(b1.y) * w1);
    o1.z = f2bf(bf2f(a1.z) * w0 + bf2f(b1.z) * w1);
    o1.w = f2bf(bf2f(a1.w) * w0 + bf2f(b1.w) * w1);
    ushort4* po = (ushort4*)(Oa + (size_t)m * 256 + c0);
    po[0] = o0; po[1] = o1;
}

// ---- epilogue: out = LN1( LN0(Oa@Wo^T + bo) + relu(LN0(...)) ), fp32 out ----
__global__ __launch_bounds__(128) void k_epi(const unsigned short* __restrict__ Oa,
                                             const unsigned short* __restrict__ W,
                                             const float* __restrict__ bo,
                                             const float* __restrict__ g0,
                                             const float* __restrict__ be0,
                                             const float* __restrict__ g1,
                                             const float* __restrict__ be1,
                                             float* __restrict__ out) {
    const int wv = threadIdx.x >> 6, lid = threadIdx.x & 63;
    const int i = lid & 15, G = lid >> 4;
    const int m0 = blockIdx.x * 32 + wv * 16;
    f32x4 acc[16];
#pragma unroll
    for (int nf = 0; nf < 16; ++nf) acc[nf] = f32x4{0.f, 0.f, 0.f, 0.f};
    const unsigned short* Arow = Oa + (size_t)(m0 + i) * 256;
#pragma unroll
    for (int k0 = 0; k0 < 256; k0 += 32) {
        s16x8 a = *(const s16x8*)(Arow + k0 + G * 8);
#pragma unroll
        for (int nf = 0; nf < 16; ++nf) {
            s16x8 b = *(const s16x8*)(W + (size_t)(nf * 16 + i) * 256 + k0 + G * 8);
            acc[nf] = MFMA_BF16(a, b, acc[nf]);
        }
    }
    f32x4 s1 = f32x4{0.f, 0.f, 0.f, 0.f}, s2 = f32x4{0.f, 0.f, 0.f, 0.f};
#pragma unroll
    for (int nf = 0; nf < 16; ++nf) {
        float bb = bo[nf * 16 + i];
#pragma unroll
        for (int r = 0; r < 4; ++r) {
            float x = acc[nf][r] + bb;
            acc[nf][r] = x;
            s1[r] += x;
            s2[r] += x * x;
        }
    }
#pragma unroll
    for (int mk = 1; mk < 16; mk <<= 1) {
#pragma unroll
        for (int r = 0; r < 4; ++r) {
            s1[r] += __shfl_xor(s1[r], mk);
            s2[r] += __shfl_xor(s2[r], mk);
        }
    }
    f32x4 mu, rs;
#pragma unroll
    for (int r = 0; r < 4; ++r) {
        mu[r] = s1[r] * (1.f / 256.f);
        float var = s2[r] * (1.f / 256.f) - mu[r] * mu[r];
        rs[r] = rsqrtf(var + 1e-5f);
    }
    f32x4 t1 = f32x4{0.f, 0.f, 0.f, 0.f}, t2 = f32x4{0.f, 0.f, 0.f, 0.f};
#pragma unroll
    for (int nf = 0; nf < 16; ++nf) {
        float gv = g0[nf * 16 + i], bv = be0[nf * 16 + i];
#pragma unroll
        for (int r = 0; r < 4; ++r) {
            float y = (acc[nf][r] - mu[r]) * rs[r] * gv + bv;
            float z = y + fmaxf(y, 0.f);
            acc[nf][r] = z;
            t1[r] += z;
            t2[r] += z * z;
        }
    }
#pragma unroll
    for (int mk = 1; mk < 16; mk <<= 1) {
#pragma unroll
        for (int r = 0; r < 4; ++r) {
            t1[r] += __shfl_xor(t1[r], mk);
            t2[r] += __shfl_xor(t2[r], mk);
        }
    }
    f32x4 mu2, rs2;
#pragma unroll
    for (int r = 0; r < 4; ++r) {
        mu2[r] = t1[r] * (1.f / 256.f);
        float var = t2[r] * (1.f / 256.f) - mu2[r] * mu2[r];
        rs2[r] = rsqrtf(var + 1e-5f);
    }
#pragma unroll
    for (int nf = 0; nf < 16; ++nf) {
        int col = nf * 16 + i;
        float gv = g1[col], bv = be1[col];
#pragma unroll
        for (int r = 0; r < 4; ++r) {
            out[(size_t)(m0 + G * 4 + r) * 256 + col] = (acc[nf][r] - mu2[r]) * rs2[r] * gv + bv;
        }
    }
}

extern "C" void kernel_launch(void* const* d_in, const int* in_sizes, int n_in,
                              void* d_out, int out_size, void* d_ws, size_t ws_size,
                              hipStream_t stream) {
    const float* Q   = (const float*)d_in[0];
    const float* K   = (const float*)d_in[1];
    const float* Wq  = (const float*)d_in[2];
    const float* bq  = (const float*)d_in[3];
    const float* Wk  = (const float*)d_in[4];
    const float* bk  = (const float*)d_in[5];
    const float* Wv  = (const float*)d_in[6];
    const float* bv  = (const float*)d_in[7];
    const float* Wo  = (const float*)d_in[8];
    const float* bo  = (const float*)d_in[9];
    const float* g0  = (const float*)d_in[10];
    const float* be0 = (const float*)d_in[11];
    const float* g1  = (const float*)d_in[12];
    const float* be1 = (const float*)d_in[13];
    float* out = (float*)d_out;

    char* ws = (char*)d_ws;
    unsigned short* Wqb = (unsigned short*)(ws + (size_t)0);
    unsigned short* Wkb = (unsigned short*)(ws + ((size_t)128 << 10));
    unsigned short* Wvb = (unsigned short*)(ws + ((size_t)256 << 10));
    unsigned short* Wob = (unsigned short*)(ws + ((size_t)384 << 10));
    size_t off = (size_t)512 << 10;
    const size_t big = (size_t)8192 * 256 * 2;  // 4 MB each
    unsigned short* Qb = (unsigned short*)(ws + off); off += big;
    unsigned short* Kb = (unsigned short*)(ws + off); off += big;
    unsigned short* Qp = (unsigned short*)(ws + off); off += big;
    unsigned short* Kp = (unsigned short*)(ws + off); off += big;
    unsigned short* Vt = (unsigned short*)(ws + off); off += big;
    unsigned short* Oa = (unsigned short*)(ws + off); off += big;
    unsigned short* Ob = (unsigned short*)(ws + off); off += 2 * big;  // split partials
    float* Lb = (float*)(ws + off); off += (size_t)2 * 16 * 4096 * 4;

    k_cvt_all<<<4352, 256, 0, stream>>>(Q, K, Wq, Wk, Wv, Wo,
                                        Qb, Kb, Wqb, Wkb, Wvb, Wob);

    const float qscale = 1.4426950408889634f / sqrtf(32.0f);
    k_proj<<<1536, 128, 0, stream>>>(Qb, Kb, Wqb, Wkb, Wvb, bq, bk, bv,
                                     Qp, Kp, Vt, qscale);

    k_attn<<<1024, 256, 0, stream>>>(Qp, Kp, Vt, Ob, Lb);
    k_comb<<<1024, 256, 0, stream>>>(Ob, Lb, Oa);

    k_epi<<<256, 128, 0, stream>>>(Oa, Wob, bo, g0, be0, g1, be1, out);
}

// Round 8
// 118.624 us; speedup vs baseline: 1.2982x; 1.2982x over previous
//
#include <hip/hip_runtime.h>
#include <hip/hip_bf16.h>
#include <math.h>

// ---------------------------------------------------------------------------
// MAB block. Attention: 32x32x16 MFMA, swapped QK^T (lane-local softmax),
// no max-shift (scores bounded), row-sums via ones-MFMA, KV-split x2.
// K/V pre-packed into MFMA fragment order by k_proj so every k_attn load is
// fully coalesced (1KB/instr). Separate k_comb (bisect: round-7 fused epilogue
// suspected in determinism failure; this round isolates the packing change).
// ---------------------------------------------------------------------------

typedef __attribute__((ext_vector_type(4))) float f32x4;
typedef __attribute__((ext_vector_type(16))) float f32x16;
typedef __attribute__((ext_vector_type(8))) short s16x8;
typedef __attribute__((ext_vector_type(2))) unsigned u32x2;

#define MFMA_BF16(A, B, C) __builtin_amdgcn_mfma_f32_16x16x32_bf16((A), (B), (C), 0, 0, 0)
#define MFMA32(A, B, C) __builtin_amdgcn_mfma_f32_32x32x16_bf16((A), (B), (C), 0, 0, 0)

static __device__ __forceinline__ unsigned short f2bf(float f) {
    union { float f; unsigned u; } v; v.f = f;
    unsigned u = v.u;
    unsigned r = (u + 0x7FFFu + ((u >> 16) & 1u)) >> 16;  // RNE
    return (unsigned short)r;
}

static __device__ __forceinline__ float bf2f(unsigned short b) {
    union { unsigned u; float f; } v; v.u = ((unsigned)b) << 16;
    return v.f;
}

static __device__ __forceinline__ unsigned cvtpk(float lo, float hi) {
    unsigned r;
    asm("v_cvt_pk_bf16_f32 %0, %1, %2" : "=v"(r) : "v"(lo), "v"(hi));
    return r;
}

static __device__ __forceinline__ s16x8 mk8(unsigned a, unsigned b, unsigned c, unsigned d) {
    union { unsigned u[4]; s16x8 v; } x;
    x.u[0] = a; x.u[1] = b; x.u[2] = c; x.u[3] = d;
    return x.v;
}

// ---- merged fp32 -> bf16 convert: Q, K, and the 4 weight matrices ----
__global__ __launch_bounds__(256) void k_cvt_all(
    const float* __restrict__ Q, const float* __restrict__ K,
    const float* __restrict__ Wq, const float* __restrict__ Wk,
    const float* __restrict__ Wv, const float* __restrict__ Wo,
    unsigned short* __restrict__ Qb, unsigned short* __restrict__ Kb,
    unsigned short* __restrict__ Wqb, unsigned short* __restrict__ Wkb,
    unsigned short* __restrict__ Wvb, unsigned short* __restrict__ Wob) {
    int bid = blockIdx.x, tid = threadIdx.x;
    const float* src;
    unsigned short* dst;
    int idx;
    if (bid < 2048) {
        src = Q; dst = Qb; idx = bid * 256 + tid;
    } else if (bid < 4096) {
        src = K; dst = Kb; idx = (bid - 2048) * 256 + tid;
    } else {
        int w = (bid - 4096) >> 6;
        src = (w == 0) ? Wq : (w == 1) ? Wk : (w == 2) ? Wv : Wo;
        dst = (w == 0) ? Wqb : (w == 1) ? Wkb : (w == 2) ? Wvb : Wob;
        idx = ((bid - 4096) & 63) * 256 + tid;
    }
    float4 v = ((const float4*)src)[idx];
    ushort4 o;
    o.x = f2bf(v.x); o.y = f2bf(v.y); o.z = f2bf(v.z); o.w = f2bf(v.w);
    ((ushort4*)dst)[idx] = o;
}

// ---- merged projections ----
// bid<256: Qp (row-major head-split, scaled). bid<512: Kf (fragment order).
// bid>=512: Vf (fragment order). Fragment order per (b,h), per 32-key tile t:
//   frag f in {0,1}, elem index = t*1024 + f*512 + lane*8 + e  where
//   K: value K[t*32 + (lane&31)][f*16 + (lane>>5)*8 + e]
//   V: value V[t*32 + f*16 + (lane>>5)*8 + e][dv = lane&31]
__global__ __launch_bounds__(128) void k_proj(
    const unsigned short* __restrict__ Qb, const unsigned short* __restrict__ Kb,
    const unsigned short* __restrict__ Wqb, const unsigned short* __restrict__ Wkb,
    const unsigned short* __restrict__ Wvb,
    const float* __restrict__ bq, const float* __restrict__ bk, const float* __restrict__ bv,
    unsigned short* __restrict__ Qp, unsigned short* __restrict__ Kf,
    unsigned short* __restrict__ Vf, float qscale) {
    const int wv = threadIdx.x >> 6, lid = threadIdx.x & 63;
    const int i = lid & 15, G = lid >> 4;
    const int bid = blockIdx.x;
    if (bid < 512) {
        const int which = bid >> 8;
        const unsigned short* X = which ? Kb : Qb;
        const unsigned short* W = which ? Wkb : Wqb;
        const float* bias = which ? bk : bq;
        const float scale = which ? 1.0f : qscale;
        const int m0 = (bid & 255) * 32 + wv * 16;
        f32x4 acc[16];
#pragma unroll
        for (int nf = 0; nf < 16; ++nf) acc[nf] = f32x4{0.f, 0.f, 0.f, 0.f};
        const unsigned short* Xrow = X + (size_t)(m0 + i) * 256;
#pragma unroll
        for (int k0 = 0; k0 < 256; k0 += 32) {
            s16x8 a = *(const s16x8*)(Xrow + k0 + G * 8);
#pragma unroll
            for (int nf = 0; nf < 16; ++nf) {
                s16x8 b = *(const s16x8*)(W + (size_t)(nf * 16 + i) * 256 + k0 + G * 8);
                acc[nf] = MFMA_BF16(a, b, acc[nf]);
            }
        }
#pragma unroll
        for (int nf = 0; nf < 16; ++nf) {
            int col = nf * 16 + i;
            float bvv = bias[col];
            int h = col >> 5, dh = col & 31;
#pragma unroll
            for (int r = 0; r < 4; ++r) {
                int m = m0 + G * 4 + r;
                int bb = m >> 12, j = m & 4095;
                float v = (acc[nf][r] + bvv) * scale;
                unsigned short bfv = f2bf(v);
                if (which == 0) {
                    Qp[(size_t)(((bb << 3) + h) * 4096 + j) * 32 + dh] = bfv;
                } else {
                    size_t off = (size_t)((bb << 3) + h) * 131072 +
                                 (size_t)(j >> 5) * 1024 + ((dh >> 4) & 1) * 512 +
                                 ((j & 31) + ((dh >> 3) & 1) * 32) * 8 + (dh & 7);
                    Kf[off] = bfv;
                }
            }
        }
    } else {
        const int tid = bid - 512;                  // [0, 1024)
        const int n0 = (tid & 127) * 64;            // 8192 rows
        const int dv0 = (tid >> 7) * 32 + wv * 16;  // 256 dv
        f32x4 acc[4];
#pragma unroll
        for (int nf = 0; nf < 4; ++nf) acc[nf] = f32x4{0.f, 0.f, 0.f, 0.f};
        const unsigned short* Wrow = Wvb + (size_t)(dv0 + i) * 256;
#pragma unroll
        for (int k0 = 0; k0 < 256; k0 += 32) {
            s16x8 a = *(const s16x8*)(Wrow + k0 + G * 8);
#pragma unroll
            for (int nf = 0; nf < 4; ++nf) {
                s16x8 b = *(const s16x8*)(Kb + (size_t)(n0 + nf * 16 + i) * 256 + k0 + G * 8);
                acc[nf] = MFMA_BF16(a, b, acc[nf]);
            }
        }
#pragma unroll
        for (int r = 0; r < 4; ++r) {
            int dv = dv0 + G * 4 + r;
            float bvv = bv[dv];
            int h = dv >> 5, dvl = dv & 31;
#pragma unroll
            for (int nf = 0; nf < 4; ++nf) {
                int j = n0 + nf * 16 + i;
                int bb = j >> 12, jj = j & 4095;
                int rem = jj & 31;
                size_t off = (size_t)((bb << 3) + h) * 131072 +
                             (size_t)(jj >> 5) * 1024 + (rem >> 4) * 512 +
                             (dvl + ((rem >> 3) & 1) * 32) * 8 + (rem & 7);
                Vf[off] = f2bf(acc[nf][r] + bvv);
            }
        }
    }
}

// ---- softmax + PV body for one 32-wide KV tile (no max-shift) ----
static __device__ __forceinline__ void softmax_pv(
    f32x16& st, f32x16& acc, f32x16& accL,
    const s16x8 v0, const s16x8 v1, const s16x8 ones) {
#pragma unroll
    for (int r = 0; r < 16; ++r) st[r] = __builtin_amdgcn_exp2f(st[r]);
    unsigned w00 = cvtpk(st[0], st[1]),   w01 = cvtpk(st[2], st[3]);
    unsigned w10 = cvtpk(st[4], st[5]),   w11 = cvtpk(st[6], st[7]);
    unsigned w20 = cvtpk(st[8], st[9]),   w21 = cvtpk(st[10], st[11]);
    unsigned w30 = cvtpk(st[12], st[13]), w31 = cvtpk(st[14], st[15]);
    u32x2 sA0 = __builtin_amdgcn_permlane32_swap(w00, w10, false, false);
    u32x2 sB0 = __builtin_amdgcn_permlane32_swap(w01, w11, false, false);
    u32x2 sA1 = __builtin_amdgcn_permlane32_swap(w20, w30, false, false);
    u32x2 sB1 = __builtin_amdgcn_permlane32_swap(w21, w31, false, false);
    s16x8 pa0 = mk8(sA0[0], sB0[0], sA0[1], sB0[1]);  // P, j half 0
    s16x8 pa1 = mk8(sA1[0], sB1[0], sA1[1], sB1[1]);  // P, j half 1
    acc  = MFMA32(pa0, v0, acc);
    acc  = MFMA32(pa1, v1, acc);
    accL = MFMA32(pa0, ones, accL);  // row-sums ride the MFMA pipe
    accL = MFMA32(pa1, ones, accL);
}

// ---- flash attention, KV-split x2, fully-coalesced fragment loads ----
__global__ __launch_bounds__(256, 4) void k_attn(const unsigned short* __restrict__ Qp,
                                                 const unsigned short* __restrict__ Kf,
                                                 const unsigned short* __restrict__ Vf,
                                                 unsigned short* __restrict__ Ob,
                                                 float* __restrict__ Lb) {
    const int wv = threadIdx.x >> 6, l = threadIdx.x & 63;
    const int ql = l & 31, hi = l >> 5;
    int bid = blockIdx.x;
    int wg = ((bid & 7) << 7) | (bid >> 3);  // XCD swizzle, 1024 % 8 == 0, bijective
    int bh = wg >> 6;
    int rest = wg & 63;
    int qblk = rest >> 1, sp = rest & 1;
    const unsigned short* Qh = Qp + (size_t)bh * 4096 * 32;
    const int q0 = qblk * 128 + wv * 32;

    s16x8 qb0 = *(const s16x8*)(Qh + (size_t)(q0 + ql) * 32 + hi * 8);
    s16x8 qb1 = *(const s16x8*)(Qh + (size_t)(q0 + ql) * 32 + 16 + hi * 8);

    f32x16 acc, accL, Z;
#pragma unroll
    for (int r = 0; r < 16; ++r) { acc[r] = 0.f; accL[r] = 0.f; Z[r] = 0.f; }
    const s16x8 ONES = mk8(0x3F803F80u, 0x3F803F80u, 0x3F803F80u, 0x3F803F80u);

    // fragment-order bases: per tile t, frag f: base + t*1024 + f*512 + l*8
    const unsigned short* Kl = Kf + (size_t)bh * 131072 + (size_t)sp * 65536 + l * 8;
    const unsigned short* Vl = Vf + (size_t)bh * 131072 + (size_t)sp * 65536 + l * 8;
    s16x8 kA0 = *(const s16x8*)(Kl + 0),    kA1 = *(const s16x8*)(Kl + 512);
    s16x8 kB0 = *(const s16x8*)(Kl + 1024), kB1 = *(const s16x8*)(Kl + 1536);
    s16x8 vA0 = *(const s16x8*)(Vl + 0),    vA1 = *(const s16x8*)(Vl + 512);
    s16x8 vB0 = *(const s16x8*)(Vl + 1024), vB1 = *(const s16x8*)(Vl + 1536);

    f32x16 st = MFMA32(kA0, qb0, Z);  // tile 0
    st = MFMA32(kA1, qb1, st);
    f32x16 stn;

    for (int t = 0; t < 64; t += 2) {
        {   // tile t (A bufs); QK(t+1) from B bufs overlaps softmax(t)
            int t2 = (t + 2 < 64) ? t + 2 : 62;
            kA0 = *(const s16x8*)(Kl + (size_t)t2 * 1024);
            kA1 = *(const s16x8*)(Kl + (size_t)t2 * 1024 + 512);
            stn = MFMA32(kB0, qb0, Z);
            stn = MFMA32(kB1, qb1, stn);
            softmax_pv(st, acc, accL, vA0, vA1, ONES);
            vA0 = *(const s16x8*)(Vl + (size_t)t2 * 1024);
            vA1 = *(const s16x8*)(Vl + (size_t)t2 * 1024 + 512);
            st = stn;
        }
        {   // tile t+1 (B bufs)
            int t2 = (t + 3 < 64) ? t + 3 : 62;
            kB0 = *(const s16x8*)(Kl + (size_t)t2 * 1024);
            kB1 = *(const s16x8*)(Kl + (size_t)t2 * 1024 + 512);
            stn = MFMA32(kA0, qb0, Z);
            stn = MFMA32(kA1, qb1, stn);
            softmax_pv(st, acc, accL, vB0, vB1, ONES);
            vB0 = *(const s16x8*)(Vl + (size_t)t2 * 1024);
            vB1 = *(const s16x8*)(Vl + (size_t)t2 * 1024 + 512);
            st = stn;
        }
    }

    // store normalized partial + row-sums
    const int bb = bh >> 3, h = bh & 7;
    unsigned short* Obs = Ob + (size_t)sp * 8192 * 256;
#pragma unroll
    for (int r = 0; r < 16; ++r) {
        int qr = (r & 3) + 8 * (r >> 2) + 4 * hi;
        float o = acc[r] / accL[r];
        Obs[(size_t)((bb << 12) + q0 + qr) * 256 + h * 32 + ql] = f2bf(o);
        if (ql == 0) Lb[(size_t)(sp * 16 + bh) * 4096 + q0 + qr] = accL[r];
    }
}

// ---- combine the two KV-split partials: O = (o0*l0 + o1*l1)/(l0+l1) ----
__global__ __launch_bounds__(256) void k_comb(const unsigned short* __restrict__ Ob,
                                              const float* __restrict__ Lb,
                                              unsigned short* __restrict__ Oa) {
    int unit = blockIdx.x * 256 + threadIdx.x;  // 262144 units x 8 cols
    int m = unit >> 5;
    int c0 = (unit & 31) << 3;
    int bb = m >> 12, q = m & 4095;
    int bh = bb * 8 + (c0 >> 5);
    float l0 = Lb[(size_t)bh * 4096 + q];
    float l1 = Lb[(size_t)(16 + bh) * 4096 + q];
    float inv = 1.f / (l0 + l1);
    float w0 = l0 * inv, w1 = l1 * inv;
    const ushort4* p0 = (const ushort4*)(Ob + (size_t)m * 256 + c0);
    const ushort4* p1 = (const ushort4*)(Ob + (size_t)8192 * 256 + (size_t)m * 256 + c0);
    ushort4 a0 = p0[0], a1 = p0[1];
    ushort4 b0 = p1[0], b1 = p1[1];
    ushort4 o0, o1;
    o0.x = f2bf(bf2f(a0.x) * w0 + bf2f(b0.x) * w1);
    o0.y = f2bf(bf2f(a0.y) * w0 + bf2f(b0.y) * w1);
    o0.z = f2bf(bf2f(a0.z) * w0 + bf2f(b0.z) * w1);
    o0.w = f2bf(bf2f(a0.w) * w0 + bf2f(b0.w) * w1);
    o1.x = f2bf(bf2f(a1.x) * w0 + bf2f(b1.x) * w1);
    o1.y = f2bf(bf2f(a1.y) * w0 + bf2f(b1.y) * w1);
    o1.z = f2bf(bf2f(a1.z) * w0 + bf2f(b1.z) * w1);
    o1.w = f2bf(bf2f(a1.w) * w0 + bf2f(b1.w) * w1);
    ushort4* po = (ushort4*)(Oa + (size_t)m * 256 + c0);
    po[0] = o0; po[1] = o1;
}

// ---- epilogue: out = LN1( LN0(Oa@Wo^T + bo) + relu(LN0(...)) ), fp32 out ----
__global__ __launch_bounds__(128) void k_epi(const unsigned short* __restrict__ Oa,
                                             const unsigned short* __restrict__ W,
                                             const float* __restrict__ bo,
                                             const float* __restrict__ g0,
                                             const float* __restrict__ be0,
                                             const float* __restrict__ g1,
                                             const float* __restrict__ be1,
                                             float* __restrict__ out) {
    const int wv = threadIdx.x >> 6, lid = threadIdx.x & 63;
    const int i = lid & 15, G = lid >> 4;
    const int m0 = blockIdx.x * 32 + wv * 16;
    f32x4 acc[16];
#pragma unroll
    for (int nf = 0; nf < 16; ++nf) acc[nf] = f32x4{0.f, 0.f, 0.f, 0.f};
    const unsigned short* Arow = Oa + (size_t)(m0 + i) * 256;
#pragma unroll
    for (int k0 = 0; k0 < 256; k0 += 32) {
        s16x8 a = *(const s16x8*)(Arow + k0 + G * 8);
#pragma unroll
        for (int nf = 0; nf < 16; ++nf) {
            s16x8 b = *(const s16x8*)(W + (size_t)(nf * 16 + i) * 256 + k0 + G * 8);
            acc[nf] = MFMA_BF16(a, b, acc[nf]);
        }
    }
    f32x4 s1 = f32x4{0.f, 0.f, 0.f, 0.f}, s2 = f32x4{0.f, 0.f, 0.f, 0.f};
#pragma unroll
    for (int nf = 0; nf < 16; ++nf) {
        float bb = bo[nf * 16 + i];
#pragma unroll
        for (int r = 0; r < 4; ++r) {
            float x = acc[nf][r] + bb;
            acc[nf][r] = x;
            s1[r] += x;
            s2[r] += x * x;
        }
    }
#pragma unroll
    for (int mk = 1; mk < 16; mk <<= 1) {
#pragma unroll
        for (int r = 0; r < 4; ++r) {
            s1[r] += __shfl_xor(s1[r], mk);
            s2[r] += __shfl_xor(s2[r], mk);
        }
    }
    f32x4 mu, rs;
#pragma unroll
    for (int r = 0; r < 4; ++r) {
        mu[r] = s1[r] * (1.f / 256.f);
        float var = s2[r] * (1.f / 256.f) - mu[r] * mu[r];
        rs[r] = rsqrtf(var + 1e-5f);
    }
    f32x4 t1 = f32x4{0.f, 0.f, 0.f, 0.f}, t2 = f32x4{0.f, 0.f, 0.f, 0.f};
#pragma unroll
    for (int nf = 0; nf < 16; ++nf) {
        float gv = g0[nf * 16 + i], bv = be0[nf * 16 + i];
#pragma unroll
        for (int r = 0; r < 4; ++r) {
            float y = (acc[nf][r] - mu[r]) * rs[r] * gv + bv;
            float z = y + fmaxf(y, 0.f);
            acc[nf][r] = z;
            t1[r] += z;
            t2[r] += z * z;
        }
    }
#pragma unroll
    for (int mk = 1; mk < 16; mk <<= 1) {
#pragma unroll
        for (int r = 0; r < 4; ++r) {
            t1[r] += __shfl_xor(t1[r], mk);
            t2[r] += __shfl_xor(t2[r], mk);
        }
    }
    f32x4 mu2, rs2;
#pragma unroll
    for (int r = 0; r < 4; ++r) {
        mu2[r] = t1[r] * (1.f / 256.f);
        float var = t2[r] * (1.f / 256.f) - mu2[r] * mu2[r];
        rs2[r] = rsqrtf(var + 1e-5f);
    }
#pragma unroll
    for (int nf = 0; nf < 16; ++nf) {
        int col = nf * 16 + i;
        float gv = g1[col], bv = be1[col];
#pragma unroll
        for (int r = 0; r < 4; ++r) {
            out[(size_t)(m0 + G * 4 + r) * 256 + col] = (acc[nf][r] - mu2[r]) * rs2[r] * gv + bv;
        }
    }
}

extern "C" void kernel_launch(void* const* d_in, const int* in_sizes, int n_in,
                              void* d_out, int out_size, void* d_ws, size_t ws_size,
                              hipStream_t stream) {
    const float* Q   = (const float*)d_in[0];
    const float* K   = (const float*)d_in[1];
    const float* Wq  = (const float*)d_in[2];
    const float* bq  = (const float*)d_in[3];
    const float* Wk  = (const float*)d_in[4];
    const float* bk  = (const float*)d_in[5];
    const float* Wv  = (const float*)d_in[6];
    const float* bv  = (const float*)d_in[7];
    const float* Wo  = (const float*)d_in[8];
    const float* bo  = (const float*)d_in[9];
    const float* g0  = (const float*)d_in[10];
    const float* be0 = (const float*)d_in[11];
    const float* g1  = (const float*)d_in[12];
    const float* be1 = (const float*)d_in[13];
    float* out = (float*)d_out;

    char* ws = (char*)d_ws;
    unsigned short* Wqb = (unsigned short*)(ws + (size_t)0);
    unsigned short* Wkb = (unsigned short*)(ws + ((size_t)128 << 10));
    unsigned short* Wvb = (unsigned short*)(ws + ((size_t)256 << 10));
    unsigned short* Wob = (unsigned short*)(ws + ((size_t)384 << 10));
    size_t off = (size_t)512 << 10;
    const size_t big = (size_t)8192 * 256 * 2;  // 4 MB each
    unsigned short* Qb = (unsigned short*)(ws + off); off += big;
    unsigned short* Kb = (unsigned short*)(ws + off); off += big;
    unsigned short* Qp = (unsigned short*)(ws + off); off += big;
    unsigned short* Kf = (unsigned short*)(ws + off); off += big;
    unsigned short* Vf = (unsigned short*)(ws + off); off += big;
    unsigned short* Oa = (unsigned short*)(ws + off); off += big;
    unsigned short* Ob = (unsigned short*)(ws + off); off += 2 * big;  // split partials
    float* Lb = (float*)(ws + off); off += (size_t)2 * 16 * 4096 * 4;

    k_cvt_all<<<4352, 256, 0, stream>>>(Q, K, Wq, Wk, Wv, Wo,
                                        Qb, Kb, Wqb, Wkb, Wvb, Wob);

    const float qscale = 1.4426950408889634f / sqrtf(32.0f);
    k_proj<<<1536, 128, 0, stream>>>(Qb, Kb, Wqb, Wkb, Wvb, bq, bk, bv,
                                     Qp, Kf, Vf, qscale);

    k_attn<<<1024, 256, 0, stream>>>(Qp, Kf, Vf, Ob, Lb);
    k_comb<<<1024, 256, 0, stream>>>(Ob, Lb, Oa);

    k_epi<<<256, 128, 0, stream>>>(Oa, Wob, bo, g0, be0, g1, be1, out);
}

// Round 10
// 117.612 us; speedup vs baseline: 1.3094x; 1.0086x over previous
//
#include <hip/hip_runtime.h>
#include <hip/hip_bf16.h>
#include <math.h>

// ---------------------------------------------------------------------------
// MAB block. Attention: 32x32x16 MFMA, swapped QK^T (lane-local softmax),
// no max-shift (scores bounded), row-sums via ones-MFMA, KV-split x4.
// K/V pre-packed into MFMA fragment order (coalesced 1KB loads).
// launch_bounds(256,4): VGPR fits 8 waves/SIMD naturally (52 regs); the
// (256,8) bound in r9 forced spills and broke correctness (bisect).
// ---------------------------------------------------------------------------

typedef __attribute__((ext_vector_type(4))) float f32x4;
typedef __attribute__((ext_vector_type(16))) float f32x16;
typedef __attribute__((ext_vector_type(8))) short s16x8;
typedef __attribute__((ext_vector_type(2))) unsigned u32x2;

#define MFMA_BF16(A, B, C) __builtin_amdgcn_mfma_f32_16x16x32_bf16((A), (B), (C), 0, 0, 0)
#define MFMA32(A, B, C) __builtin_amdgcn_mfma_f32_32x32x16_bf16((A), (B), (C), 0, 0, 0)

static __device__ __forceinline__ unsigned short f2bf(float f) {
    union { float f; unsigned u; } v; v.f = f;
    unsigned u = v.u;
    unsigned r = (u + 0x7FFFu + ((u >> 16) & 1u)) >> 16;  // RNE
    return (unsigned short)r;
}

static __device__ __forceinline__ float bf2f(unsigned short b) {
    union { unsigned u; float f; } v; v.u = ((unsigned)b) << 16;
    return v.f;
}

static __device__ __forceinline__ unsigned cvtpk(float lo, float hi) {
    unsigned r;
    asm("v_cvt_pk_bf16_f32 %0, %1, %2" : "=v"(r) : "v"(lo), "v"(hi));
    return r;
}

static __device__ __forceinline__ s16x8 mk8(unsigned a, unsigned b, unsigned c, unsigned d) {
    union { unsigned u[4]; s16x8 v; } x;
    x.u[0] = a; x.u[1] = b; x.u[2] = c; x.u[3] = d;
    return x.v;
}

// ---- fp32 -> bf16 convert: K and the 4 weight matrices (Q fused into k_proj) ----
__global__ __launch_bounds__(256) void k_cvt_all(
    const float* __restrict__ K,
    const float* __restrict__ Wq, const float* __restrict__ Wk,
    const float* __restrict__ Wv, const float* __restrict__ Wo,
    unsigned short* __restrict__ Kb,
    unsigned short* __restrict__ Wqb, unsigned short* __restrict__ Wkb,
    unsigned short* __restrict__ Wvb, unsigned short* __restrict__ Wob) {
    int bid = blockIdx.x, tid = threadIdx.x;
    const float* src;
    unsigned short* dst;
    int idx;
    if (bid < 2048) {
        src = K; dst = Kb; idx = bid * 256 + tid;
    } else {
        int w = (bid - 2048) >> 6;
        src = (w == 0) ? Wq : (w == 1) ? Wk : (w == 2) ? Wv : Wo;
        dst = (w == 0) ? Wqb : (w == 1) ? Wkb : (w == 2) ? Wvb : Wob;
        idx = ((bid - 2048) & 63) * 256 + tid;
    }
    float4 v = ((const float4*)src)[idx];
    ushort4 o;
    o.x = f2bf(v.x); o.y = f2bf(v.y); o.z = f2bf(v.z); o.w = f2bf(v.w);
    ((ushort4*)dst)[idx] = o;
}

// ---- merged projections ----
// bid<256: Qp from fp32 Q (inline cvt). bid<512: Kf (fragment order).
// bid>=512: Vf (fragment order). Fragment order per (b,h), per 32-key tile t:
//   frag f in {0,1}, elem index = t*1024 + f*512 + lane*8 + e
__global__ __launch_bounds__(128) void k_proj(
    const float* __restrict__ Qf, const unsigned short* __restrict__ Kb,
    const unsigned short* __restrict__ Wqb, const unsigned short* __restrict__ Wkb,
    const unsigned short* __restrict__ Wvb,
    const float* __restrict__ bq, const float* __restrict__ bk, const float* __restrict__ bv,
    unsigned short* __restrict__ Qp, unsigned short* __restrict__ Kf,
    unsigned short* __restrict__ Vf, float qscale) {
    const int wv = threadIdx.x >> 6, lid = threadIdx.x & 63;
    const int i = lid & 15, G = lid >> 4;
    const int bid = blockIdx.x;
    if (bid < 512) {
        const int which = bid >> 8;
        const unsigned short* W = which ? Wkb : Wqb;
        const float* bias = which ? bk : bq;
        const float scale = which ? 1.0f : qscale;
        const int m0 = (bid & 255) * 32 + wv * 16;
        f32x4 acc[16];
#pragma unroll
        for (int nf = 0; nf < 16; ++nf) acc[nf] = f32x4{0.f, 0.f, 0.f, 0.f};
        const unsigned short* Xrow = Kb + (size_t)(m0 + i) * 256;
        const float* Qrow = Qf + (size_t)(m0 + i) * 256;
#pragma unroll
        for (int k0 = 0; k0 < 256; k0 += 32) {
            s16x8 a;
            if (which) {
                a = *(const s16x8*)(Xrow + k0 + G * 8);
            } else {
                float4 f0 = *(const float4*)(Qrow + k0 + G * 8);
                float4 f1 = *(const float4*)(Qrow + k0 + G * 8 + 4);
                a = mk8(cvtpk(f0.x, f0.y), cvtpk(f0.z, f0.w),
                        cvtpk(f1.x, f1.y), cvtpk(f1.z, f1.w));
            }
#pragma unroll
            for (int nf = 0; nf < 16; ++nf) {
                s16x8 b = *(const s16x8*)(W + (size_t)(nf * 16 + i) * 256 + k0 + G * 8);
                acc[nf] = MFMA_BF16(a, b, acc[nf]);
            }
        }
#pragma unroll
        for (int nf = 0; nf < 16; ++nf) {
            int col = nf * 16 + i;
            float bvv = bias[col];
            int h = col >> 5, dh = col & 31;
#pragma unroll
            for (int r = 0; r < 4; ++r) {
                int m = m0 + G * 4 + r;
                int bb = m >> 12, j = m & 4095;
                float v = (acc[nf][r] + bvv) * scale;
                unsigned short bfv = f2bf(v);
                if (which == 0) {
                    Qp[(size_t)(((bb << 3) + h) * 4096 + j) * 32 + dh] = bfv;
                } else {
                    size_t off = (size_t)((bb << 3) + h) * 131072 +
                                 (size_t)(j >> 5) * 1024 + ((dh >> 4) & 1) * 512 +
                                 ((j & 31) + ((dh >> 3) & 1) * 32) * 8 + (dh & 7);
                    Kf[off] = bfv;
                }
            }
        }
    } else {
        const int tid = bid - 512;                  // [0, 1024)
        const int n0 = (tid & 127) * 64;            // 8192 rows
        const int dv0 = (tid >> 7) * 32 + wv * 16;  // 256 dv
        f32x4 acc[4];
#pragma unroll
        for (int nf = 0; nf < 4; ++nf) acc[nf] = f32x4{0.f, 0.f, 0.f, 0.f};
        const unsigned short* Wrow = Wvb + (size_t)(dv0 + i) * 256;
#pragma unroll
        for (int k0 = 0; k0 < 256; k0 += 32) {
            s16x8 a = *(const s16x8*)(Wrow + k0 + G * 8);
#pragma unroll
            for (int nf = 0; nf < 4; ++nf) {
                s16x8 b = *(const s16x8*)(Kb + (size_t)(n0 + nf * 16 + i) * 256 + k0 + G * 8);
                acc[nf] = MFMA_BF16(a, b, acc[nf]);
            }
        }
#pragma unroll
        for (int r = 0; r < 4; ++r) {
            int dv = dv0 + G * 4 + r;
            float bvv = bv[dv];
            int h = dv >> 5, dvl = dv & 31;
#pragma unroll
            for (int nf = 0; nf < 4; ++nf) {
                int j = n0 + nf * 16 + i;
                int bb = j >> 12, jj = j & 4095;
                int rem = jj & 31;
                size_t off = (size_t)((bb << 3) + h) * 131072 +
                             (size_t)(jj >> 5) * 1024 + (rem >> 4) * 512 +
                             (dvl + ((rem >> 3) & 1) * 32) * 8 + (rem & 7);
                Vf[off] = f2bf(acc[nf][r] + bvv);
            }
        }
    }
}

// ---- softmax + PV body for one 32-wide KV tile (no max-shift) ----
static __device__ __forceinline__ void softmax_pv(
    f32x16& st, f32x16& acc, f32x16& accL,
    const s16x8 v0, const s16x8 v1, const s16x8 ones) {
#pragma unroll
    for (int r = 0; r < 16; ++r) st[r] = __builtin_amdgcn_exp2f(st[r]);
    unsigned w00 = cvtpk(st[0], st[1]),   w01 = cvtpk(st[2], st[3]);
    unsigned w10 = cvtpk(st[4], st[5]),   w11 = cvtpk(st[6], st[7]);
    unsigned w20 = cvtpk(st[8], st[9]),   w21 = cvtpk(st[10], st[11]);
    unsigned w30 = cvtpk(st[12], st[13]), w31 = cvtpk(st[14], st[15]);
    u32x2 sA0 = __builtin_amdgcn_permlane32_swap(w00, w10, false, false);
    u32x2 sB0 = __builtin_amdgcn_permlane32_swap(w01, w11, false, false);
    u32x2 sA1 = __builtin_amdgcn_permlane32_swap(w20, w30, false, false);
    u32x2 sB1 = __builtin_amdgcn_permlane32_swap(w21, w31, false, false);
    s16x8 pa0 = mk8(sA0[0], sB0[0], sA0[1], sB0[1]);  // P, j half 0
    s16x8 pa1 = mk8(sA1[0], sB1[0], sA1[1], sB1[1]);  // P, j half 1
    acc  = MFMA32(pa0, v0, acc);
    acc  = MFMA32(pa1, v1, acc);
    accL = MFMA32(pa0, ones, accL);  // row-sums ride the MFMA pipe
    accL = MFMA32(pa1, ones, accL);
}

// ---- flash attention, KV-split x4 (1024 keys/block), grid 2048 ----
__global__ __launch_bounds__(256, 4) void k_attn(const unsigned short* __restrict__ Qp,
                                                 const unsigned short* __restrict__ Kf,
                                                 const unsigned short* __restrict__ Vf,
                                                 unsigned short* __restrict__ Ob,
                                                 float* __restrict__ Lb) {
    const int wv = threadIdx.x >> 6, l = threadIdx.x & 63;
    const int ql = l & 31, hi = l >> 5;
    int bid = blockIdx.x;
    int wg = ((bid & 7) << 8) | (bid >> 3);  // XCD swizzle, 2048 % 8 == 0, bijective
    int bh = wg >> 7;
    int rest = wg & 127;
    int qblk = rest >> 2, sp = rest & 3;
    const unsigned short* Qh = Qp + (size_t)bh * 4096 * 32;
    const int q0 = qblk * 128 + wv * 32;

    s16x8 qb0 = *(const s16x8*)(Qh + (size_t)(q0 + ql) * 32 + hi * 8);
    s16x8 qb1 = *(const s16x8*)(Qh + (size_t)(q0 + ql) * 32 + 16 + hi * 8);

    f32x16 acc, accL, Z;
#pragma unroll
    for (int r = 0; r < 16; ++r) { acc[r] = 0.f; accL[r] = 0.f; Z[r] = 0.f; }
    const s16x8 ONES = mk8(0x3F803F80u, 0x3F803F80u, 0x3F803F80u, 0x3F803F80u);

    // fragment-order bases: per tile t, frag f: base + t*1024 + f*512 + l*8
    const unsigned short* Kl = Kf + (size_t)bh * 131072 + (size_t)sp * 32768 + l * 8;
    const unsigned short* Vl = Vf + (size_t)bh * 131072 + (size_t)sp * 32768 + l * 8;
    s16x8 kA0 = *(const s16x8*)(Kl + 0),    kA1 = *(const s16x8*)(Kl + 512);
    s16x8 kB0 = *(const s16x8*)(Kl + 1024), kB1 = *(const s16x8*)(Kl + 1536);
    s16x8 vA0 = *(const s16x8*)(Vl + 0),    vA1 = *(const s16x8*)(Vl + 512);
    s16x8 vB0 = *(const s16x8*)(Vl + 1024), vB1 = *(const s16x8*)(Vl + 1536);

    f32x16 st = MFMA32(kA0, qb0, Z);  // tile 0
    st = MFMA32(kA1, qb1, st);
    f32x16 stn;

    for (int t = 0; t < 32; t += 2) {
        {   // tile t (A bufs); QK(t+1) from B bufs overlaps softmax(t)
            int t2 = (t + 2 < 32) ? t + 2 : 30;
            kA0 = *(const s16x8*)(Kl + (size_t)t2 * 1024);
            kA1 = *(const s16x8*)(Kl + (size_t)t2 * 1024 + 512);
            stn = MFMA32(kB0, qb0, Z);
            stn = MFMA32(kB1, qb1, stn);
            softmax_pv(st, acc, accL, vA0, vA1, ONES);
            vA0 = *(const s16x8*)(Vl + (size_t)t2 * 1024);
            vA1 = *(const s16x8*)(Vl + (size_t)t2 * 1024 + 512);
            st = stn;
        }
        {   // tile t+1 (B bufs)
            int t2 = (t + 3 < 32) ? t + 3 : 30;
            kB0 = *(const s16x8*)(Kl + (size_t)t2 * 1024);
            kB1 = *(const s16x8*)(Kl + (size_t)t2 * 1024 + 512);
            stn = MFMA32(kA0, qb0, Z);
            stn = MFMA32(kA1, qb1, stn);
            softmax_pv(st, acc, accL, vB0, vB1, ONES);
            vB0 = *(const s16x8*)(Vl + (size_t)t2 * 1024);
            vB1 = *(const s16x8*)(Vl + (size_t)t2 * 1024 + 512);
            st = stn;
        }
    }

    // store normalized partial + row-sums
    const int bb = bh >> 3, h = bh & 7;
    unsigned short* Obs = Ob + (size_t)sp * 8192 * 256;
#pragma unroll
    for (int r = 0; r < 16; ++r) {
        int qr = (r & 3) + 8 * (r >> 2) + 4 * hi;
        float o = acc[r] / accL[r];
        Obs[(size_t)((bb << 12) + q0 + qr) * 256 + h * 32 + ql] = f2bf(o);
        if (ql == 0) Lb[(size_t)(sp * 16 + bh) * 4096 + q0 + qr] = accL[r];
    }
}

// ---- combine the four KV-split partials: O = sum(l_i o_i) / sum(l_i) ----
__global__ __launch_bounds__(256) void k_comb(const unsigned short* __restrict__ Ob,
                                              const float* __restrict__ Lb,
                                              unsigned short* __restrict__ Oa) {
    int unit = blockIdx.x * 256 + threadIdx.x;  // 262144 units x 8 cols
    int m = unit >> 5;
    int c0 = (unit & 31) << 3;
    int bb = m >> 12, q = m & 4095;
    int bh = bb * 8 + (c0 >> 5);
    float l0 = Lb[(size_t)(0 * 16 + bh) * 4096 + q];
    float l1 = Lb[(size_t)(1 * 16 + bh) * 4096 + q];
    float l2 = Lb[(size_t)(2 * 16 + bh) * 4096 + q];
    float l3 = Lb[(size_t)(3 * 16 + bh) * 4096 + q];
    float inv = 1.f / (l0 + l1 + l2 + l3);
    float w[4] = {l0 * inv, l1 * inv, l2 * inv, l3 * inv};
    float o[8] = {0.f, 0.f, 0.f, 0.f, 0.f, 0.f, 0.f, 0.f};
#pragma unroll
    for (int sp = 0; sp < 4; ++sp) {
        const ushort4* p = (const ushort4*)(Ob + (size_t)sp * 8192 * 256 + (size_t)m * 256 + c0);
        ushort4 a0 = p[0], a1 = p[1];
        o[0] += bf2f(a0.x) * w[sp]; o[1] += bf2f(a0.y) * w[sp];
        o[2] += bf2f(a0.z) * w[sp]; o[3] += bf2f(a0.w) * w[sp];
        o[4] += bf2f(a1.x) * w[sp]; o[5] += bf2f(a1.y) * w[sp];
        o[6] += bf2f(a1.z) * w[sp]; o[7] += bf2f(a1.w) * w[sp];
    }
    ushort4 r0, r1;
    r0.x = f2bf(o[0]); r0.y = f2bf(o[1]); r0.z = f2bf(o[2]); r0.w = f2bf(o[3]);
    r1.x = f2bf(o[4]); r1.y = f2bf(o[5]); r1.z = f2bf(o[6]); r1.w = f2bf(o[7]);
    ushort4* po = (ushort4*)(Oa + (size_t)m * 256 + c0);
    po[0] = r0; po[1] = r1;
}

// ---- epilogue: out = LN1( LN0(Oa@Wo^T + bo) + relu(LN0(...)) ), fp32 out ----
__global__ __launch_bounds__(128) void k_epi(const unsigned short* __restrict__ Oa,
                                             const unsigned short* __restrict__ W,
                                             const float* __restrict__ bo,
                                             const float* __restrict__ g0,
                                             const float* __restrict__ be0,
                                             const float* __restrict__ g1,
                                             const float* __restrict__ be1,
                                             float* __restrict__ out) {
    const int wv = threadIdx.x >> 6, lid = threadIdx.x & 63;
    const int i = lid & 15, G = lid >> 4;
    const int m0 = blockIdx.x * 32 + wv * 16;
    f32x4 acc[16];
#pragma unroll
    for (int nf = 0; nf < 16; ++nf) acc[nf] = f32x4{0.f, 0.f, 0.f, 0.f};
    const unsigned short* Arow = Oa + (size_t)(m0 + i) * 256;
#pragma unroll
    for (int k0 = 0; k0 < 256; k0 += 32) {
        s16x8 a = *(const s16x8*)(Arow + k0 + G * 8);
#pragma unroll
        for (int nf = 0; nf < 16; ++nf) {
            s16x8 b = *(const s16x8*)(W + (size_t)(nf * 16 + i) * 256 + k0 + G * 8);
            acc[nf] = MFMA_BF16(a, b, acc[nf]);
        }
    }
    f32x4 s1 = f32x4{0.f, 0.f, 0.f, 0.f}, s2 = f32x4{0.f, 0.f, 0.f, 0.f};
#pragma unroll
    for (int nf = 0; nf < 16; ++nf) {
        float bb = bo[nf * 16 + i];
#pragma unroll
        for (int r = 0; r < 4; ++r) {
            float x = acc[nf][r] + bb;
            acc[nf][r] = x;
            s1[r] += x;
            s2[r] += x * x;
        }
    }
#pragma unroll
    for (int mk = 1; mk < 16; mk <<= 1) {
#pragma unroll
        for (int r = 0; r < 4; ++r) {
            s1[r] += __shfl_xor(s1[r], mk);
            s2[r] += __shfl_xor(s2[r], mk);
        }
    }
    f32x4 mu, rs;
#pragma unroll
    for (int r = 0; r < 4; ++r) {
        mu[r] = s1[r] * (1.f / 256.f);
        float var = s2[r] * (1.f / 256.f) - mu[r] * mu[r];
        rs[r] = rsqrtf(var + 1e-5f);
    }
    f32x4 t1 = f32x4{0.f, 0.f, 0.f, 0.f}, t2 = f32x4{0.f, 0.f, 0.f, 0.f};
#pragma unroll
    for (int nf = 0; nf < 16; ++nf) {
        float gv = g0[nf * 16 + i], bv = be0[nf * 16 + i];
#pragma unroll
        for (int r = 0; r < 4; ++r) {
            float y = (acc[nf][r] - mu[r]) * rs[r] * gv + bv;
            float z = y + fmaxf(y, 0.f);
            acc[nf][r] = z;
            t1[r] += z;
            t2[r] += z * z;
        }
    }
#pragma unroll
    for (int mk = 1; mk < 16; mk <<= 1) {
#pragma unroll
        for (int r = 0; r < 4; ++r) {
            t1[r] += __shfl_xor(t1[r], mk);
            t2[r] += __shfl_xor(t2[r], mk);
        }
    }
    f32x4 mu2, rs2;
#pragma unroll
    for (int r = 0; r < 4; ++r) {
        mu2[r] = t1[r] * (1.f / 256.f);
        float var = t2[r] * (1.f / 256.f) - mu2[r] * mu2[r];
        rs2[r] = rsqrtf(var + 1e-5f);
    }
#pragma unroll
    for (int nf = 0; nf < 16; ++nf) {
        int col = nf * 16 + i;
        float gv = g1[col], bv = be1[col];
#pragma unroll
        for (int r = 0; r < 4; ++r) {
            out[(size_t)(m0 + G * 4 + r) * 256 + col] = (acc[nf][r] - mu2[r]) * rs2[r] * gv + bv;
        }
    }
}

extern "C" void kernel_launch(void* const* d_in, const int* in_sizes, int n_in,
                              void* d_out, int out_size, void* d_ws, size_t ws_size,
                              hipStream_t stream) {
    const float* Q   = (const float*)d_in[0];
    const float* K   = (const float*)d_in[1];
    const float* Wq  = (const float*)d_in[2];
    const float* bq  = (const float*)d_in[3];
    const float* Wk  = (const float*)d_in[4];
    const float* bk  = (const float*)d_in[5];
    const float* Wv  = (const float*)d_in[6];
    const float* bv  = (const float*)d_in[7];
    const float* Wo  = (const float*)d_in[8];
    const float* bo  = (const float*)d_in[9];
    const float* g0  = (const float*)d_in[10];
    const float* be0 = (const float*)d_in[11];
    const float* g1  = (const float*)d_in[12];
    const float* be1 = (const float*)d_in[13];
    float* out = (float*)d_out;

    char* ws = (char*)d_ws;
    unsigned short* Wqb = (unsigned short*)(ws + (size_t)0);
    unsigned short* Wkb = (unsigned short*)(ws + ((size_t)128 << 10));
    unsigned short* Wvb = (unsigned short*)(ws + ((size_t)256 << 10));
    unsigned short* Wob = (unsigned short*)(ws + ((size_t)384 << 10));
    size_t off = (size_t)512 << 10;
    const size_t big = (size_t)8192 * 256 * 2;  // 4 MB each
    unsigned short* Kb = (unsigned short*)(ws + off); off += big;
    unsigned short* Qp = (unsigned short*)(ws + off); off += big;
    unsigned short* Kf = (unsigned short*)(ws + off); off += big;
    unsigned short* Vf = (unsigned short*)(ws + off); off += big;
    unsigned short* Oa = (unsigned short*)(ws + off); off += big;
    unsigned short* Ob = (unsigned short*)(ws + off); off += 4 * big;  // 4 split partials
    float* Lb = (float*)(ws + off); off += (size_t)4 * 16 * 4096 * 4;

    k_cvt_all<<<2304, 256, 0, stream>>>(K, Wq, Wk, Wv, Wo,
                                        Kb, Wqb, Wkb, Wvb, Wob);

    const float qscale = 1.4426950408889634f / sqrtf(32.0f);
    k_proj<<<1536, 128, 0, stream>>>(Q, Kb, Wqb, Wkb, Wvb, bq, bk, bv,
                                     Qp, Kf, Vf, qscale);

    k_attn<<<2048, 256, 0, stream>>>(Qp, Kf, Vf, Ob, Lb);
    k_comb<<<1024, 256, 0, stream>>>(Ob, Lb, Oa);

    k_epi<<<256, 128, 0, stream>>>(Oa, Wob, bo, g0, be0, g1, be1, out);
}

// Round 13
// 106.425 us; speedup vs baseline: 1.4470x; 1.1051x over previous
//
#include <hip/hip_runtime.h>
#include <hip/hip_bf16.h>
#include <math.h>

// ---------------------------------------------------------------------------
// MAB block. Attention: 32x32x16 MFMA, swapped QK^T (lane-local softmax),
// no max-shift (scores bounded), row-sums via ones-MFMA, KV-split x2.
// K/V AND all weight matrices pre-packed into MFMA fragment order so every
// GEMM B-fragment load is lane-contiguous (1KB/instr). Conversion runs in a
// dedicated cvt kernel (scalar f2bf) — mass inline-asm cvt in GEMM loops
// miscompiles (r11/r12 NaN). Separate k_comb (r7: fused epi nondeterministic).
// ---------------------------------------------------------------------------

typedef __attribute__((ext_vector_type(4))) float f32x4;
typedef __attribute__((ext_vector_type(16))) float f32x16;
typedef __attribute__((ext_vector_type(8))) short s16x8;
typedef __attribute__((ext_vector_type(2))) unsigned u32x2;

#define MFMA_BF16(A, B, C) __builtin_amdgcn_mfma_f32_16x16x32_bf16((A), (B), (C), 0, 0, 0)
#define MFMA32(A, B, C) __builtin_amdgcn_mfma_f32_32x32x16_bf16((A), (B), (C), 0, 0, 0)

static __device__ __forceinline__ unsigned short f2bf(float f) {
    union { float f; unsigned u; } v; v.f = f;
    unsigned u = v.u;
    unsigned r = (u + 0x7FFFu + ((u >> 16) & 1u)) >> 16;  // RNE
    return (unsigned short)r;
}

static __device__ __forceinline__ float bf2f(unsigned short b) {
    union { unsigned u; float f; } v; v.u = ((unsigned)b) << 16;
    return v.f;
}

static __device__ __forceinline__ unsigned cvtpk(float lo, float hi) {
    unsigned r;
    asm("v_cvt_pk_bf16_f32 %0, %1, %2" : "=v"(r) : "v"(lo), "v"(hi));
    return r;
}

static __device__ __forceinline__ s16x8 mk8(unsigned a, unsigned b, unsigned c, unsigned d) {
    union { unsigned u[4]; s16x8 v; } x;
    x.u[0] = a; x.u[1] = b; x.u[2] = c; x.u[3] = d;
    return x.v;
}

// ---- fp32 -> bf16 convert: K (linear) + 4 weights (FRAGMENT-PACKED) ----
// Packed W layout (256x256 row-major source W[row][col]):
//   dst[(row>>4)*4096 + (col>>5)*512 + ((col>>3)&3)*128 + (row&15)*8 + (col&7)]
// so a wave's b-fragment load for (nf, k0) is dst + nf*4096 + (k0>>5)*512 + lane*8.
__global__ __launch_bounds__(256) void k_cvt_all(
    const float* __restrict__ K,
    const float* __restrict__ Wq, const float* __restrict__ Wk,
    const float* __restrict__ Wv, const float* __restrict__ Wo,
    unsigned short* __restrict__ Kb,
    unsigned short* __restrict__ Wqf, unsigned short* __restrict__ Wkf,
    unsigned short* __restrict__ Wvf, unsigned short* __restrict__ Wof) {
    int bid = blockIdx.x, tid = threadIdx.x;
    if (bid < 2048) {
        int idx = bid * 256 + tid;
        float4 v = ((const float4*)K)[idx];
        ushort4 o;
        o.x = f2bf(v.x); o.y = f2bf(v.y); o.z = f2bf(v.z); o.w = f2bf(v.w);
        ((ushort4*)Kb)[idx] = o;
    } else {
        int w = (bid - 2048) >> 6;
        const float* src = (w == 0) ? Wq : (w == 1) ? Wk : (w == 2) ? Wv : Wo;
        unsigned short* dst = (w == 0) ? Wqf : (w == 1) ? Wkf : (w == 2) ? Wvf : Wof;
        int idx = ((bid - 2048) & 63) * 256 + tid;
        int s = idx * 4;
        int row = s >> 8, col = s & 255;
        float4 v = ((const float4*)src)[idx];
        size_t d = (size_t)(row >> 4) * 4096 + ((size_t)(col >> 5) << 9) +
                   (((col >> 3) & 3) << 7) + ((row & 15) << 3) + (col & 7);
        ushort4 o;
        o.x = f2bf(v.x); o.y = f2bf(v.y); o.z = f2bf(v.z); o.w = f2bf(v.w);
        *(ushort4*)(dst + d) = o;  // col%8 in {0,4} -> 8B-aligned, contiguous
    }
}

// ---- merged projections ----
// bid<256: Qp from fp32 Q (inline cvt, r10-proven). bid<512: Kf (fragment
// order). bid>=512: Vf (fragment order). K/V fragment order per (b,h), per
// 32-key tile t: frag f in {0,1}, elem index = t*1024 + f*512 + lane*8 + e.
// All W b/a-fragments read from packed W (lane-contiguous).
__global__ __launch_bounds__(128) void k_proj(
    const float* __restrict__ Qf, const unsigned short* __restrict__ Kb,
    const unsigned short* __restrict__ Wqf, const unsigned short* __restrict__ Wkf,
    const unsigned short* __restrict__ Wvf,
    const float* __restrict__ bq, const float* __restrict__ bk, const float* __restrict__ bv,
    unsigned short* __restrict__ Qp, unsigned short* __restrict__ Kf,
    unsigned short* __restrict__ Vf, float qscale) {
    const int wv = threadIdx.x >> 6, lid = threadIdx.x & 63;
    const int i = lid & 15, G = lid >> 4;
    const int bid = blockIdx.x;
    if (bid < 512) {
        const int which = bid >> 8;
        const unsigned short* W = which ? Wkf : Wqf;
        const float* bias = which ? bk : bq;
        const float scale = which ? 1.0f : qscale;
        const int m0 = (bid & 255) * 32 + wv * 16;
        f32x4 acc[16];
#pragma unroll
        for (int nf = 0; nf < 16; ++nf) acc[nf] = f32x4{0.f, 0.f, 0.f, 0.f};
        const unsigned short* Xrow = Kb + (size_t)(m0 + i) * 256;
        const float* Qrow = Qf + (size_t)(m0 + i) * 256;
#pragma unroll
        for (int k0 = 0; k0 < 256; k0 += 32) {
            s16x8 a;
            if (which) {
                a = *(const s16x8*)(Xrow + k0 + G * 8);
            } else {
                float4 f0 = *(const float4*)(Qrow + k0 + G * 8);
                float4 f1 = *(const float4*)(Qrow + k0 + G * 8 + 4);
                a = mk8(cvtpk(f0.x, f0.y), cvtpk(f0.z, f0.w),
                        cvtpk(f1.x, f1.y), cvtpk(f1.z, f1.w));
            }
#pragma unroll
            for (int nf = 0; nf < 16; ++nf) {
                s16x8 b = *(const s16x8*)(W + nf * 4096 + ((k0 >> 5) << 9) + lid * 8);
                acc[nf] = MFMA_BF16(a, b, acc[nf]);
            }
        }
#pragma unroll
        for (int nf = 0; nf < 16; ++nf) {
            int col = nf * 16 + i;
            float bvv = bias[col];
            int h = col >> 5, dh = col & 31;
#pragma unroll
            for (int r = 0; r < 4; ++r) {
                int m = m0 + G * 4 + r;
                int bb = m >> 12, j = m & 4095;
                float v = (acc[nf][r] + bvv) * scale;
                unsigned short bfv = f2bf(v);
                if (which == 0) {
                    Qp[(size_t)(((bb << 3) + h) * 4096 + j) * 32 + dh] = bfv;
                } else {
                    size_t off = (size_t)((bb << 3) + h) * 131072 +
                                 (size_t)(j >> 5) * 1024 + ((dh >> 4) & 1) * 512 +
                                 ((j & 31) + ((dh >> 3) & 1) * 32) * 8 + (dh & 7);
                    Kf[off] = bfv;
                }
            }
        }
    } else {
        const int tid = bid - 512;                  // [0, 1024)
        const int n0 = (tid & 127) * 64;            // 8192 rows
        const int dv0 = (tid >> 7) * 32 + wv * 16;  // 256 dv
        f32x4 acc[4];
#pragma unroll
        for (int nf = 0; nf < 4; ++nf) acc[nf] = f32x4{0.f, 0.f, 0.f, 0.f};
        // packed Wv a-fragment: row block (dv0>>4) = (tid>>7)*2 + wv
        const unsigned short* Wvp = Wvf + (size_t)((tid >> 7) * 2 + wv) * 4096;
#pragma unroll
        for (int k0 = 0; k0 < 256; k0 += 32) {
            s16x8 a = *(const s16x8*)(Wvp + ((k0 >> 5) << 9) + lid * 8);
#pragma unroll
            for (int nf = 0; nf < 4; ++nf) {
                s16x8 b = *(const s16x8*)(Kb + (size_t)(n0 + nf * 16 + i) * 256 + k0 + G * 8);
                acc[nf] = MFMA_BF16(a, b, acc[nf]);
            }
        }
#pragma unroll
        for (int r = 0; r < 4; ++r) {
            int dv = dv0 + G * 4 + r;
            float bvv = bv[dv];
            int h = dv >> 5, dvl = dv & 31;
#pragma unroll
            for (int nf = 0; nf < 4; ++nf) {
                int j = n0 + nf * 16 + i;
                int bb = j >> 12, jj = j & 4095;
                int rem = jj & 31;
                size_t off = (size_t)((bb << 3) + h) * 131072 +
                             (size_t)(jj >> 5) * 1024 + (rem >> 4) * 512 +
                             (dvl + ((rem >> 3) & 1) * 32) * 8 + (rem & 7);
                Vf[off] = f2bf(acc[nf][r] + bvv);
            }
        }
    }
}

// ---- softmax + PV body for one 32-wide KV tile (no max-shift; r8-proven) ----
static __device__ __forceinline__ void softmax_pv(
    f32x16& st, f32x16& acc, f32x16& accL,
    const s16x8 v0, const s16x8 v1, const s16x8 ones) {
#pragma unroll
    for (int r = 0; r < 16; ++r) st[r] = __builtin_amdgcn_exp2f(st[r]);
    unsigned w00 = cvtpk(st[0], st[1]),   w01 = cvtpk(st[2], st[3]);
    unsigned w10 = cvtpk(st[4], st[5]),   w11 = cvtpk(st[6], st[7]);
    unsigned w20 = cvtpk(st[8], st[9]),   w21 = cvtpk(st[10], st[11]);
    unsigned w30 = cvtpk(st[12], st[13]), w31 = cvtpk(st[14], st[15]);
    u32x2 sA0 = __builtin_amdgcn_permlane32_swap(w00, w10, false, false);
    u32x2 sB0 = __builtin_amdgcn_permlane32_swap(w01, w11, false, false);
    u32x2 sA1 = __builtin_amdgcn_permlane32_swap(w20, w30, false, false);
    u32x2 sB1 = __builtin_amdgcn_permlane32_swap(w21, w31, false, false);
    s16x8 pa0 = mk8(sA0[0], sB0[0], sA0[1], sB0[1]);  // P, j half 0
    s16x8 pa1 = mk8(sA1[0], sB1[0], sA1[1], sB1[1]);  // P, j half 1
    acc  = MFMA32(pa0, v0, acc);
    acc  = MFMA32(pa1, v1, acc);
    accL = MFMA32(pa0, ones, accL);  // row-sums ride the MFMA pipe
    accL = MFMA32(pa1, ones, accL);
}

// ---- flash attention, KV-split x2 (2048 keys/block), grid 1024 (r8-proven) ----
__global__ __launch_bounds__(256, 4) void k_attn(const unsigned short* __restrict__ Qp,
                                                 const unsigned short* __restrict__ Kf,
                                                 const unsigned short* __restrict__ Vf,
                                                 unsigned short* __restrict__ Ob,
                                                 float* __restrict__ Lb) {
    const int wv = threadIdx.x >> 6, l = threadIdx.x & 63;
    const int ql = l & 31, hi = l >> 5;
    int bid = blockIdx.x;
    int wg = ((bid & 7) << 7) | (bid >> 3);  // XCD swizzle, 1024 % 8 == 0, bijective
    int bh = wg >> 6;
    int rest = wg & 63;
    int qblk = rest >> 1, sp = rest & 1;
    const unsigned short* Qh = Qp + (size_t)bh * 4096 * 32;
    const int q0 = qblk * 128 + wv * 32;

    s16x8 qb0 = *(const s16x8*)(Qh + (size_t)(q0 + ql) * 32 + hi * 8);
    s16x8 qb1 = *(const s16x8*)(Qh + (size_t)(q0 + ql) * 32 + 16 + hi * 8);

    f32x16 acc, accL, Z;
#pragma unroll
    for (int r = 0; r < 16; ++r) { acc[r] = 0.f; accL[r] = 0.f; Z[r] = 0.f; }
    const s16x8 ONES = mk8(0x3F803F80u, 0x3F803F80u, 0x3F803F80u, 0x3F803F80u);

    // fragment-order bases: per tile t, frag f: base + t*1024 + f*512 + l*8
    const unsigned short* Kl = Kf + (size_t)bh * 131072 + (size_t)sp * 65536 + l * 8;
    const unsigned short* Vl = Vf + (size_t)bh * 131072 + (size_t)sp * 65536 + l * 8;
    s16x8 kA0 = *(const s16x8*)(Kl + 0),    kA1 = *(const s16x8*)(Kl + 512);
    s16x8 kB0 = *(const s16x8*)(Kl + 1024), kB1 = *(const s16x8*)(Kl + 1536);
    s16x8 vA0 = *(const s16x8*)(Vl + 0),    vA1 = *(const s16x8*)(Vl + 512);
    s16x8 vB0 = *(const s16x8*)(Vl + 1024), vB1 = *(const s16x8*)(Vl + 1536);

    f32x16 st = MFMA32(kA0, qb0, Z);  // tile 0
    st = MFMA32(kA1, qb1, st);
    f32x16 stn;

    for (int t = 0; t < 64; t += 2) {
        {   // tile t (A bufs); QK(t+1) from B bufs overlaps softmax(t)
            int t2 = (t + 2 < 64) ? t + 2 : 62;
            kA0 = *(const s16x8*)(Kl + (size_t)t2 * 1024);
            kA1 = *(const s16x8*)(Kl + (size_t)t2 * 1024 + 512);
            stn = MFMA32(kB0, qb0, Z);
            stn = MFMA32(kB1, qb1, stn);
            softmax_pv(st, acc, accL, vA0, vA1, ONES);
            vA0 = *(const s16x8*)(Vl + (size_t)t2 * 1024);
            vA1 = *(const s16x8*)(Vl + (size_t)t2 * 1024 + 512);
            st = stn;
        }
        {   // tile t+1 (B bufs)
            int t2 = (t + 3 < 64) ? t + 3 : 62;
            kB0 = *(const s16x8*)(Kl + (size_t)t2 * 1024);
            kB1 = *(const s16x8*)(Kl + (size_t)t2 * 1024 + 512);
            stn = MFMA32(kA0, qb0, Z);
            stn = MFMA32(kA1, qb1, stn);
            softmax_pv(st, acc, accL, vB0, vB1, ONES);
            vB0 = *(const s16x8*)(Vl + (size_t)t2 * 1024);
            vB1 = *(const s16x8*)(Vl + (size_t)t2 * 1024 + 512);
            st = stn;
        }
    }

    // store normalized partial + row-sums
    const int bb = bh >> 3, h = bh & 7;
    unsigned short* Obs = Ob + (size_t)sp * 8192 * 256;
#pragma unroll
    for (int r = 0; r < 16; ++r) {
        int qr = (r & 3) + 8 * (r >> 2) + 4 * hi;
        float o = acc[r] / accL[r];
        Obs[(size_t)((bb << 12) + q0 + qr) * 256 + h * 32 + ql] = f2bf(o);
        if (ql == 0) Lb[(size_t)(sp * 16 + bh) * 4096 + q0 + qr] = accL[r];
    }
}

// ---- combine the two KV-split partials: O = (o0*l0 + o1*l1)/(l0+l1) ----
__global__ __launch_bounds__(256) void k_comb(const unsigned short* __restrict__ Ob,
                                              const float* __restrict__ Lb,
                                              unsigned short* __restrict__ Oa) {
    int unit = blockIdx.x * 256 + threadIdx.x;  // 262144 units x 8 cols
    int m = unit >> 5;
    int c0 = (unit & 31) << 3;
    int bb = m >> 12, q = m & 4095;
    int bh = bb * 8 + (c0 >> 5);
    float l0 = Lb[(size_t)bh * 4096 + q];
    float l1 = Lb[(size_t)(16 + bh) * 4096 + q];
    float inv = 1.f / (l0 + l1);
    float w0 = l0 * inv, w1 = l1 * inv;
    const ushort4* p0 = (const ushort4*)(Ob + (size_t)m * 256 + c0);
    const ushort4* p1 = (const ushort4*)(Ob + (size_t)8192 * 256 + (size_t)m * 256 + c0);
    ushort4 a0 = p0[0], a1 = p0[1];
    ushort4 b0 = p1[0], b1 = p1[1];
    ushort4 o0, o1;
    o0.x = f2bf(bf2f(a0.x) * w0 + bf2f(b0.x) * w1);
    o0.y = f2bf(bf2f(a0.y) * w0 + bf2f(b0.y) * w1);
    o0.z = f2bf(bf2f(a0.z) * w0 + bf2f(b0.z) * w1);
    o0.w = f2bf(bf2f(a0.w) * w0 + bf2f(b0.w) * w1);
    o1.x = f2bf(bf2f(a1.x) * w0 + bf2f(b1.x) * w1);
    o1.y = f2bf(bf2f(a1.y) * w0 + bf2f(b1.y) * w1);
    o1.z = f2bf(bf2f(a1.z) * w0 + bf2f(b1.z) * w1);
    o1.w = f2bf(bf2f(a1.w) * w0 + bf2f(b1.w) * w1);
    ushort4* po = (ushort4*)(Oa + (size_t)m * 256 + c0);
    po[0] = o0; po[1] = o1;
}

// ---- epilogue: Wo GEMM (packed bf16 Wo) + LN0 + relu-res + LN1 ----
__global__ __launch_bounds__(128) void k_epi(const unsigned short* __restrict__ Oa,
                                             const unsigned short* __restrict__ W,
                                             const float* __restrict__ bo,
                                             const float* __restrict__ g0,
                                             const float* __restrict__ be0,
                                             const float* __restrict__ g1,
                                             const float* __restrict__ be1,
                                             float* __restrict__ out) {
    const int wv = threadIdx.x >> 6, lid = threadIdx.x & 63;
    const int i = lid & 15, G = lid >> 4;
    const int m0 = blockIdx.x * 32 + wv * 16;
    f32x4 acc[16];
#pragma unroll
    for (int nf = 0; nf < 16; ++nf) acc[nf] = f32x4{0.f, 0.f, 0.f, 0.f};
    const unsigned short* Arow = Oa + (size_t)(m0 + i) * 256;
#pragma unroll
    for (int k0 = 0; k0 < 256; k0 += 32) {
        s16x8 a = *(const s16x8*)(Arow + k0 + G * 8);
#pragma unroll
        for (int nf = 0; nf < 16; ++nf) {
            s16x8 b = *(const s16x8*)(W + nf * 4096 + ((k0 >> 5) << 9) + lid * 8);
            acc[nf] = MFMA_BF16(a, b, acc[nf]);
        }
    }
    f32x4 s1 = f32x4{0.f, 0.f, 0.f, 0.f}, s2 = f32x4{0.f, 0.f, 0.f, 0.f};
#pragma unroll
    for (int nf = 0; nf < 16; ++nf) {
        float bb = bo[nf * 16 + i];
#pragma unroll
        for (int r = 0; r < 4; ++r) {
            float x = acc[nf][r] + bb;
            acc[nf][r] = x;
            s1[r] += x;
            s2[r] += x * x;
        }
    }
#pragma unroll
    for (int mk = 1; mk < 16; mk <<= 1) {
#pragma unroll
        for (int r = 0; r < 4; ++r) {
            s1[r] += __shfl_xor(s1[r], mk);
            s2[r] += __shfl_xor(s2[r], mk);
        }
    }
    f32x4 mu, rs;
#pragma unroll
    for (int r = 0; r < 4; ++r) {
        mu[r] = s1[r] * (1.f / 256.f);
        float var = s2[r] * (1.f / 256.f) - mu[r] * mu[r];
        rs[r] = rsqrtf(var + 1e-5f);
    }
    f32x4 t1 = f32x4{0.f, 0.f, 0.f, 0.f}, t2 = f32x4{0.f, 0.f, 0.f, 0.f};
#pragma unroll
    for (int nf = 0; nf < 16; ++nf) {
        float gv = g0[nf * 16 + i], bv = be0[nf * 16 + i];
#pragma unroll
        for (int r = 0; r < 4; ++r) {
            float y = (acc[nf][r] - mu[r]) * rs[r] * gv + bv;
            float z = y + fmaxf(y, 0.f);
            acc[nf][r] = z;
            t1[r] += z;
            t2[r] += z * z;
        }
    }
#pragma unroll
    for (int mk = 1; mk < 16; mk <<= 1) {
#pragma unroll
        for (int r = 0; r < 4; ++r) {
            t1[r] += __shfl_xor(t1[r], mk);
            t2[r] += __shfl_xor(t2[r], mk);
        }
    }
    f32x4 mu2, rs2;
#pragma unroll
    for (int r = 0; r < 4; ++r) {
        mu2[r] = t1[r] * (1.f / 256.f);
        float var = t2[r] * (1.f / 256.f) - mu2[r] * mu2[r];
        rs2[r] = rsqrtf(var + 1e-5f);
    }
#pragma unroll
    for (int nf = 0; nf < 16; ++nf) {
        int col = nf * 16 + i;
        float gv = g1[col], bv = be1[col];
#pragma unroll
        for (int r = 0; r < 4; ++r) {
            out[(size_t)(m0 + G * 4 + r) * 256 + col] = (acc[nf][r] - mu2[r]) * rs2[r] * gv + bv;
        }
    }
}

extern "C" void kernel_launch(void* const* d_in, const int* in_sizes, int n_in,
                              void* d_out, int out_size, void* d_ws, size_t ws_size,
                              hipStream_t stream) {
    const float* Q   = (const float*)d_in[0];
    const float* K   = (const float*)d_in[1];
    const float* Wq  = (const float*)d_in[2];
    const float* bq  = (const float*)d_in[3];
    const float* Wk  = (const float*)d_in[4];
    const float* bk  = (const float*)d_in[5];
    const float* Wv  = (const float*)d_in[6];
    const float* bv  = (const float*)d_in[7];
    const float* Wo  = (const float*)d_in[8];
    const float* bo  = (const float*)d_in[9];
    const float* g0  = (const float*)d_in[10];
    const float* be0 = (const float*)d_in[11];
    const float* g1  = (const float*)d_in[12];
    const float* be1 = (const float*)d_in[13];
    float* out = (float*)d_out;

    char* ws = (char*)d_ws;
    unsigned short* Wqf = (unsigned short*)(ws + (size_t)0);
    unsigned short* Wkf = (unsigned short*)(ws + ((size_t)128 << 10));
    unsigned short* Wvf = (unsigned short*)(ws + ((size_t)256 << 10));
    unsigned short* Wof = (unsigned short*)(ws + ((size_t)384 << 10));
    size_t off = (size_t)512 << 10;
    const size_t big = (size_t)8192 * 256 * 2;  // 4 MB each
    unsigned short* Kb = (unsigned short*)(ws + off); off += big;
    unsigned short* Qp = (unsigned short*)(ws + off); off += big;
    unsigned short* Kf = (unsigned short*)(ws + off); off += big;
    unsigned short* Vf = (unsigned short*)(ws + off); off += big;
    unsigned short* Oa = (unsigned short*)(ws + off); off += big;
    unsigned short* Ob = (unsigned short*)(ws + off); off += 2 * big;  // split partials
    float* Lb = (float*)(ws + off); off += (size_t)2 * 16 * 4096 * 4;

    k_cvt_all<<<2304, 256, 0, stream>>>(K, Wq, Wk, Wv, Wo,
                                        Kb, Wqf, Wkf, Wvf, Wof);

    const float qscale = 1.4426950408889634f / sqrtf(32.0f);
    k_proj<<<1536, 128, 0, stream>>>(Q, Kb, Wqf, Wkf, Wvf, bq, bk, bv,
                                     Qp, Kf, Vf, qscale);

    k_attn<<<1024, 256, 0, stream>>>(Qp, Kf, Vf, Ob, Lb);
    k_comb<<<1024, 256, 0, stream>>>(Ob, Lb, Oa);

    k_epi<<<256, 128, 0, stream>>>(Oa, Wof, bo, g0, be0, g1, be1, out);
}